// Round 5
// baseline (93.236 us; speedup 1.0000x reference)
//
#include <hip/hip_runtime.h>
#include <hip/hip_bf16.h>
#include <math.h>

// Problem constants
#define S_LEN 16384
#define E_DIM 2048
#define H_DIM 1024
#define G_DIM 4096
#define C_DIM 5

#define NB 512                 // blocks; 2/CU co-resident guaranteed
#define NT 512                 // threads (8 waves)
#define ROWS_PER_BLK (S_LEN / NB)   // 32
#define NFIN 16                // colsum finisher blocks
#define FIN_COLS (E_DIM / NFIN)     // 128

// ws layout: 1024 B counters | partial 4 MB | colsum 8 KB | g0 16 KB | g1 16 KB
#define CTR_BYTES 1024

__device__ __forceinline__ float dload(const float* p) {
  return __hip_atomic_load((float*)p, __ATOMIC_RELAXED, __HIP_MEMORY_SCOPE_AGENT);
}
__device__ __forceinline__ void dstore(float* p, float v) {
  __hip_atomic_store(p, v, __ATOMIC_RELAXED, __HIP_MEMORY_SCOPE_AGENT);
}
__device__ __forceinline__ int aload(int* p) {
  return __hip_atomic_load(p, __ATOMIC_RELAXED, __HIP_MEMORY_SCOPE_AGENT);
}
__device__ __forceinline__ void spin_until(int* ctr, int target) {
  for (int it = 0; it < (1 << 22); ++it) {
    if (aload(ctr) >= target) return;
    __builtin_amdgcn_s_sleep(2);
  }
}

__device__ __forceinline__ float wave_sum(float v) {
#pragma unroll
  for (int off = 32; off > 0; off >>= 1) v += __shfl_down(v, off);
  return v;
}
__device__ __forceinline__ float dot4(float4 a, float4 b) {
  return a.x * b.x + a.y * b.y + a.z * b.z + a.w * b.w;
}
__device__ __forceinline__ float sigm(float x) { return 1.f / (1.f + expf(-x)); }

__global__ __launch_bounds__(NT, 4) void decoder_persist_k(
    const float* __restrict__ enc,
    const float* __restrict__ hidden, const float* __restrict__ c_in,
    const float* __restrict__ w_ih_l0, const float* __restrict__ w_hh_l0,
    const float* __restrict__ b_ih_l0, const float* __restrict__ b_hh_l0,
    const float* __restrict__ w_ih_l1, const float* __restrict__ w_hh_l1,
    const float* __restrict__ b_ih_l1, const float* __restrict__ b_hh_l1,
    const float* __restrict__ fc_w, const float* __restrict__ fc_b,
    int* __restrict__ ctr, float* __restrict__ partial,
    float* __restrict__ colsum, float* __restrict__ g0,
    float* __restrict__ g1, float* __restrict__ out) {
  __shared__ __align__(16) float xs[E_DIM];   // colsum copy / staging (8 KB)
  __shared__ __align__(16) float h1s[H_DIM];  // h1 / h2 (4 KB)
  __shared__ float red2[NT];                  // finisher + fc reduce (2 KB)
  __shared__ int tk;

  const int tid = threadIdx.x;
  const int b = blockIdx.x;
  const int wave = tid >> 6;
  const int lane = tid & 63;
  const int row = b * 8 + wave;  // this wave's gate row (0..4095)

  // ---- Phase A: colsum partial over rows [b*32, b*32+32). Thread = f4-col.
  {
    const float4* enc4 = (const float4*)enc;
    float4 acc = {0.f, 0.f, 0.f, 0.f};
    size_t base = (size_t)b * ROWS_PER_BLK * (E_DIM / 4) + tid;
#pragma unroll 8
    for (int r = 0; r < ROWS_PER_BLK; ++r) {
      float4 v = enc4[base + (size_t)r * (E_DIM / 4)];
      acc.x += v.x; acc.y += v.y; acc.z += v.z; acc.w += v.w;
    }
    ((float4*)xs)[tid] = acc;  // stage so stores coalesce linearly
    __syncthreads();
#pragma unroll 4
    for (int i = 0; i < 4; ++i)
      dstore(&partial[(size_t)b * E_DIM + i * NT + tid], xs[i * NT + tid]);
  }
  asm volatile("s_waitcnt vmcnt(0)" ::: "memory");
  __syncthreads();
  if (tid == 0)
    tk = __hip_atomic_fetch_add(&ctr[0], 1, __ATOMIC_RELAXED,
                                __HIP_MEMORY_SCOPE_AGENT);
  __syncthreads();
  const int ticket = tk;

  // ---- Phase B (overlap): hh-part of gates0 — independent of colsum.
  float hh = 0.f;
  {
    const float4* h0g = (const float4*)hidden;
    const float4* wh = (const float4*)w_hh_l0 + (size_t)row * 256;
#pragma unroll
    for (int k = lane; k < 256; k += 64) hh += dot4(wh[k], h0g[k]);
  }

  // ---- Phase C: last-16 arrivals finish the colsum (their wait is shortest).
  if (ticket >= NB - NFIN) {
    int f = ticket - (NB - NFIN);  // 0..15: columns [f*128, f*128+128)
    if (tid == 0) spin_until(&ctr[0], NB);
    __syncthreads();
    int col = f * FIN_COLS + (tid & 127);
    int grp = tid >> 7;  // 0..3, chunks grp*128..grp*128+127
    float a = 0.f;
#pragma unroll 8
    for (int c = grp * 128; c < grp * 128 + 128; ++c)
      a += dload(&partial[(size_t)c * E_DIM + col]);
    red2[grp * 128 + (tid & 127)] = a;
    __syncthreads();
    if (tid < 128) {
      float s = (red2[tid] + red2[128 + tid]) + (red2[256 + tid] + red2[384 + tid]);
      dstore(&colsum[f * FIN_COLS + tid], s);
    }
    asm volatile("s_waitcnt vmcnt(0)" ::: "memory");
    __syncthreads();
    if (tid == 0)
      (void)__hip_atomic_fetch_add(&ctr[16], 1, __ATOMIC_RELAXED,
                                   __HIP_MEMORY_SCOPE_AGENT);
  }

  // ---- Phase D: wait for colsum; ih-part of gates0; emit g0.
  if (tid == 0) spin_until(&ctr[16], NFIN);
  __syncthreads();
#pragma unroll 4
  for (int i = 0; i < 4; ++i) xs[i * NT + tid] = dload(&colsum[i * NT + tid]);
  __syncthreads();
  {
    float ih = 0.f;
    const float4* wi = (const float4*)w_ih_l0 + (size_t)row * 512;
    const float4* xs4 = (const float4*)xs;
#pragma unroll
    for (int k = lane; k < 512; k += 64) ih += dot4(wi[k], xs4[k]);
    float tot = wave_sum(ih + hh);
    if (lane == 0) dstore(&g0[row], tot + b_ih_l0[row] + b_hh_l0[row]);
  }
  asm volatile("s_waitcnt vmcnt(0)" ::: "memory");
  __syncthreads();
  if (tid == 0)
    (void)__hip_atomic_fetch_add(&ctr[32], 1, __ATOMIC_RELAXED,
                                 __HIP_MEMORY_SCOPE_AGENT);

  // ---- Phase E: wait for all g0; cell0 (redundant per block, cheap).
  if (tid == 0) spin_until(&ctr[32], NB);
  __syncthreads();
#pragma unroll
  for (int u = 0; u < 2; ++u) {
    int j = tid + u * NT;
    float ig = dload(&g0[j]);
    float fg = dload(&g0[H_DIM + j]);
    float gg = dload(&g0[2 * H_DIM + j]);
    float og = dload(&g0[3 * H_DIM + j]);
    float c2 = sigm(fg) * c_in[j] + sigm(ig) * tanhf(gg);
    h1s[j] = sigm(og) * tanhf(c2);
  }
  __syncthreads();

  // ---- Phase F: gates1; emit g1.
  {
    const float4* h1g = (const float4*)(hidden + H_DIM);
    const float4* h14 = (const float4*)h1s;
    const float4* wi = (const float4*)w_ih_l1 + (size_t)row * 256;
    const float4* wh = (const float4*)w_hh_l1 + (size_t)row * 256;
    float a = 0.f;
#pragma unroll
    for (int k = lane; k < 256; k += 64) a += dot4(wi[k], h14[k]) + dot4(wh[k], h1g[k]);
    float tot = wave_sum(a);
    if (lane == 0) dstore(&g1[row], tot + b_ih_l1[row] + b_hh_l1[row]);
  }
  asm volatile("s_waitcnt vmcnt(0)" ::: "memory");
  __syncthreads();
  if (tid == 0)
    (void)__hip_atomic_fetch_add(&ctr[48], 1, __ATOMIC_RELAXED,
                                 __HIP_MEMORY_SCOPE_AGENT);

  // ---- Phase G: blocks 0..4 — cell1 (redundant) + one FC output each.
  if (b < C_DIM) {
    if (tid == 0) spin_until(&ctr[48], NB);
    __syncthreads();
    const float* c1 = c_in + H_DIM;
#pragma unroll
    for (int u = 0; u < 2; ++u) {
      int j = tid + u * NT;
      float ig = dload(&g1[j]);
      float fg = dload(&g1[H_DIM + j]);
      float gg = dload(&g1[2 * H_DIM + j]);
      float og = dload(&g1[3 * H_DIM + j]);
      float c2 = sigm(fg) * c1[j] + sigm(ig) * tanhf(gg);
      h1s[j] = sigm(og) * tanhf(c2);  // h2 (reuse h1s; barrier below)
    }
    __syncthreads();
    float p = fc_w[(size_t)b * H_DIM + tid] * h1s[tid] +
              fc_w[(size_t)b * H_DIM + NT + tid] * h1s[NT + tid];
    red2[tid] = p;
    __syncthreads();
#pragma unroll
    for (int s = NT / 2; s > 0; s >>= 1) {
      if (tid < s) red2[tid] += red2[tid + s];
      __syncthreads();
    }
    if (tid == 0) out[b] = red2[0] + fc_b[b];
  }
}

// ---------------------------------------------------------------------------
extern "C" void kernel_launch(void* const* d_in, const int* in_sizes, int n_in,
                              void* d_out, int out_size, void* d_ws, size_t ws_size,
                              hipStream_t stream) {
  const float* enc     = (const float*)d_in[0];   // (S,1,E)
  const float* hidden  = (const float*)d_in[1];   // (2,1,H)
  const float* c_in    = (const float*)d_in[2];   // (2,1,H)
  // d_in[3] attn_w, d_in[4] attn_b: dead (softmax over size-1 axis == 1)
  const float* w_ih_l0 = (const float*)d_in[5];
  const float* w_hh_l0 = (const float*)d_in[6];
  const float* b_ih_l0 = (const float*)d_in[7];
  const float* b_hh_l0 = (const float*)d_in[8];
  const float* w_ih_l1 = (const float*)d_in[9];
  const float* w_hh_l1 = (const float*)d_in[10];
  const float* b_ih_l1 = (const float*)d_in[11];
  const float* b_hh_l1 = (const float*)d_in[12];
  const float* fc_w    = (const float*)d_in[13];
  const float* fc_b    = (const float*)d_in[14];

  int* ctr = (int*)d_ws;
  float* partial = (float*)((char*)d_ws + CTR_BYTES);       // NB*E_DIM floats
  float* colsum  = partial + (size_t)NB * E_DIM;            // 2048
  float* g0      = colsum + E_DIM;                          // 4096
  float* g1      = g0 + G_DIM;                              // 4096
  float* out     = (float*)d_out;

  // reset counters (captured into the graph; runs before the kernel each replay)
  hipMemsetAsync(d_ws, 0, CTR_BYTES, stream);

  decoder_persist_k<<<NB, NT, 0, stream>>>(
      enc, hidden, c_in, w_ih_l0, w_hh_l0, b_ih_l0, b_hh_l0,
      w_ih_l1, w_hh_l1, b_ih_l1, b_hh_l1, fc_w, fc_b,
      ctr, partial, colsum, g0, g1, out);
}

// Round 7
// 56.705 us; speedup vs baseline: 1.6442x; 1.6442x over previous
//
#include <hip/hip_runtime.h>
#include <hip/hip_bf16.h>
#include <math.h>

// Problem constants
#define S_LEN 16384
#define E_DIM 2048
#define H_DIM 1024
#define G_DIM 4096   // 4*H
#define C_DIM 5

// Column-sum geometry: 1024 blocks = 2 col-halves x 512 chunks x 32 rows.
#define CS_CHUNKS 512
#define CS_ROWS   (S_LEN / CS_CHUNKS)   // 32

// workspace layout (float offsets)
#define WS_PART   0                              // CS_CHUNKS*E_DIM (4 MB)
#define WS_COLSUM (WS_PART + CS_CHUNKS * E_DIM)  // 2048
#define WS_HH0    (WS_COLSUM + E_DIM)            // 4096 (w_hh_l0@h0 + biases)
#define WS_HH1    (WS_HH0 + G_DIM)               // 4096 (w_hh_l1@h1in + biases)
#define WS_G0     (WS_HH1 + G_DIM)               // 4096
#define WS_G1     (WS_G0 + G_DIM)                // 4096

typedef float fvec4 __attribute__((ext_vector_type(4)));  // builtin-compatible

__device__ __forceinline__ float wave_sum(float v) {
#pragma unroll
  for (int off = 32; off > 0; off >>= 1) v += __shfl_down(v, off);
  return v;
}
__device__ __forceinline__ float dot4(float4 a, float4 b) {
  return a.x * b.x + a.y * b.y + a.z * b.z + a.w * b.w;
}
__device__ __forceinline__ float sigm(float x) { return 1.f / (1.f + expf(-x)); }

// ---------------------------------------------------------------------------
// K1: one streaming dispatch for ALL colsum-independent traffic (160 MB):
//   blocks [0,1024):    colsum partials of enc (128 MB)
//   blocks [1024,2048): hh0[row] = w_hh_l0[row,:]@hidden[0] + b_ih0 + b_hh0
//   blocks [2048,3072): hh1[row] = w_hh_l1[row,:]@hidden[1] + b_ih1 + b_hh1
__global__ __launch_bounds__(256) void stream_k(
    const fvec4* __restrict__ enc, const float4* __restrict__ hidden,
    const float4* __restrict__ w_hh_l0,
    const float* __restrict__ b_ih_l0, const float* __restrict__ b_hh_l0,
    const float4* __restrict__ w_hh_l1,
    const float* __restrict__ b_ih_l1, const float* __restrict__ b_hh_l1,
    fvec4* __restrict__ part, float* __restrict__ hh0,
    float* __restrict__ hh1) {
  int b = blockIdx.x;
  if (b < 1024) {
    // colsum partial: col-half (b&1), chunk (b>>1), 32 rows, float4/thread
    int e4 = (b & 1) * 256 + threadIdx.x;  // 0..511
    int chunk = b >> 1;
    fvec4 acc = {0.f, 0.f, 0.f, 0.f};
    size_t base = (size_t)chunk * CS_ROWS * 512 + e4;
#pragma unroll 8
    for (int r = 0; r < CS_ROWS; ++r) {
      fvec4 v = __builtin_nontemporal_load(&enc[base + (size_t)r * 512]);
      acc += v;
    }
    part[(size_t)chunk * 512 + e4] = acc;
  } else {
    // recurrent matvec: wave per row, 4 rows/block
    int which = (b >= 2048) ? 1 : 0;
    int wave = threadIdx.x >> 6;
    int lane = threadIdx.x & 63;
    int row = ((b & 1023) << 2) + wave;  // 0..4095
    const float4* w = (which ? w_hh_l1 : w_hh_l0) + (size_t)row * 256;
    const float4* h = hidden + (which ? 256 : 0);
    float a = 0.f;
#pragma unroll
    for (int k = lane; k < 256; k += 64) a += dot4(w[k], h[k]);
    a = wave_sum(a);
    if (lane == 0) {
      float bias = which ? (b_ih_l1[row] + b_hh_l1[row])
                         : (b_ih_l0[row] + b_hh_l0[row]);
      (which ? hh1 : hh0)[row] = a + bias;
    }
  }
}

// ---------------------------------------------------------------------------
// K2: reduce CS_CHUNKS partials -> colsum. 32 blocks x 256 threads.
// Block b covers float-cols [64b, 64b+64); fixed-order LDS combine.
__global__ __launch_bounds__(256) void colsum_final_k(
    const float* __restrict__ part, float* __restrict__ colsum) {
  __shared__ float red[4][64];
  int lane = threadIdx.x & 63;
  int grp = threadIdx.x >> 6;           // 0..3
  int col = blockIdx.x * 64 + lane;     // 0..2047
  float acc = 0.f;
  int c0 = grp * (CS_CHUNKS / 4);
#pragma unroll 8
  for (int ch = c0; ch < c0 + CS_CHUNKS / 4; ++ch)
    acc += part[(size_t)ch * E_DIM + col];
  red[grp][lane] = acc;
  __syncthreads();
  if (threadIdx.x < 64) {
    float s = (red[0][lane] + red[1][lane]) + (red[2][lane] + red[3][lane]);
    colsum[col] = s;
  }
}

// ---------------------------------------------------------------------------
// K3: g0[row] = w_ih_l0[row,:] @ colsum + hh0[row]   (w_hh+biases prefolded)
__global__ __launch_bounds__(256) void gates0_k(
    const float4* __restrict__ w_ih, const float4* __restrict__ x,
    const float* __restrict__ hh0, float* __restrict__ g0) {
  int wave = threadIdx.x >> 6;
  int lane = threadIdx.x & 63;
  int row = blockIdx.x * 4 + wave;  // < 4096
  const float4* wi = w_ih + (size_t)row * 512;
  float a = 0.f;
#pragma unroll
  for (int k = lane; k < 512; k += 64) a += dot4(wi[k], x[k]);
  a = wave_sum(a);
  if (lane == 0) g0[row] = a + hh0[row];
}

// ---------------------------------------------------------------------------
// K4: cell-0 prologue (h1 into LDS, redundant per block), then
//     g1[row] = w_ih_l1[row,:] @ h1 + hh1[row]
__global__ __launch_bounds__(256) void gates1_cell0_k(
    const float* __restrict__ g0, const float* __restrict__ c0,
    const float4* __restrict__ w_ih, const float* __restrict__ hh1,
    float* __restrict__ g1) {
  __shared__ __align__(16) float h1s[H_DIM];
#pragma unroll
  for (int k = 0; k < 4; ++k) {
    int j = threadIdx.x + 256 * k;
    float ig = g0[j], fg = g0[H_DIM + j], gg = g0[2 * H_DIM + j],
          og = g0[3 * H_DIM + j];
    float c2 = sigm(fg) * c0[j] + sigm(ig) * tanhf(gg);
    h1s[j] = sigm(og) * tanhf(c2);
  }
  __syncthreads();

  int wave = threadIdx.x >> 6;
  int lane = threadIdx.x & 63;
  int row = blockIdx.x * 4 + wave;  // < 4096
  const float4* h14 = (const float4*)h1s;
  const float4* wi = w_ih + (size_t)row * 256;
  float a = 0.f;
#pragma unroll
  for (int k = lane; k < 256; k += 64) a += dot4(wi[k], h14[k]);
  a = wave_sum(a);
  if (lane == 0) g1[row] = a + hh1[row];
}

// ---------------------------------------------------------------------------
// K5: cell-1 prologue (h2 into LDS), then out[r] = fc_w[r,:].h2 + fc_b[r]
__global__ __launch_bounds__(512) void fc_cell1_k(
    const float* __restrict__ g1, const float* __restrict__ c1,
    const float4* __restrict__ fc_w, const float* __restrict__ fc_b,
    float* __restrict__ out) {
  __shared__ __align__(16) float h2s[H_DIM];
#pragma unroll
  for (int k = 0; k < 2; ++k) {
    int j = threadIdx.x + 512 * k;
    float ig = g1[j], fg = g1[H_DIM + j], gg = g1[2 * H_DIM + j],
          og = g1[3 * H_DIM + j];
    float c2 = sigm(fg) * c1[j] + sigm(ig) * tanhf(gg);
    h2s[j] = sigm(og) * tanhf(c2);
  }
  __syncthreads();

  int wave = threadIdx.x >> 6;  // 0..7
  int lane = threadIdx.x & 63;
  if (wave < C_DIM) {
    const float4* h24 = (const float4*)h2s;
    const float4* wr = fc_w + (size_t)wave * 256;
    float acc = 0.f;
#pragma unroll
    for (int k = lane; k < 256; k += 64) acc += dot4(wr[k], h24[k]);
    acc = wave_sum(acc);
    if (lane == 0) out[wave] = acc + fc_b[wave];
  }
}

// ---------------------------------------------------------------------------
extern "C" void kernel_launch(void* const* d_in, const int* in_sizes, int n_in,
                              void* d_out, int out_size, void* d_ws, size_t ws_size,
                              hipStream_t stream) {
  const float* enc     = (const float*)d_in[0];   // (S,1,E)
  const float* hidden  = (const float*)d_in[1];   // (2,1,H)
  const float* c_in    = (const float*)d_in[2];   // (2,1,H)
  // d_in[3] attn_w, d_in[4] attn_b: dead (softmax over size-1 axis == 1)
  const float* w_ih_l0 = (const float*)d_in[5];   // (4H, E)
  const float* w_hh_l0 = (const float*)d_in[6];   // (4H, H)
  const float* b_ih_l0 = (const float*)d_in[7];
  const float* b_hh_l0 = (const float*)d_in[8];
  const float* w_ih_l1 = (const float*)d_in[9];   // (4H, H)
  const float* w_hh_l1 = (const float*)d_in[10];  // (4H, H)
  const float* b_ih_l1 = (const float*)d_in[11];
  const float* b_hh_l1 = (const float*)d_in[12];
  const float* fc_w    = (const float*)d_in[13];  // (C, H)
  const float* fc_b    = (const float*)d_in[14];

  float* ws = (float*)d_ws;
  float* part   = ws + WS_PART;
  float* colsum = ws + WS_COLSUM;
  float* hh0    = ws + WS_HH0;
  float* hh1    = ws + WS_HH1;
  float* g0     = ws + WS_G0;
  float* g1     = ws + WS_G1;
  float* out    = (float*)d_out;

  // K1: 160 MB of colsum-independent streaming (enc + both w_hh matvecs)
  stream_k<<<3072, 256, 0, stream>>>(
      (const fvec4*)enc, (const float4*)hidden,
      (const float4*)w_hh_l0, b_ih_l0, b_hh_l0,
      (const float4*)w_hh_l1, b_ih_l1, b_hh_l1,
      (fvec4*)part, hh0, hh1);

  // K2: partials -> colsum
  colsum_final_k<<<E_DIM / 64, 256, 0, stream>>>(part, colsum);

  // K3: gates0 (ih part only; hh+biases prefolded)
  gates0_k<<<G_DIM / 4, 256, 0, stream>>>(
      (const float4*)w_ih_l0, (const float4*)colsum, hh0, g0);

  // K4: cell-0 (fused) + gates1 ih part
  gates1_cell0_k<<<G_DIM / 4, 256, 0, stream>>>(
      g0, c_in, (const float4*)w_ih_l1, hh1, g1);

  // K5: cell-1 (fused) + FC
  fc_cell1_k<<<1, 512, 0, stream>>>(
      g1, c_in + H_DIM, (const float4*)fc_w, fc_b, out);
}

// Round 8
// 55.493 us; speedup vs baseline: 1.6801x; 1.0218x over previous
//
#include <hip/hip_runtime.h>
#include <hip/hip_bf16.h>
#include <math.h>

// Problem constants
#define S_LEN 16384
#define E_DIM 2048
#define H_DIM 1024
#define G_DIM 4096   // 4*H
#define C_DIM 5

// Column-sum geometry: 1024 blocks = 2 col-halves x 512 chunks x 32 rows.
#define CS_CHUNKS 512
#define CS_ROWS   (S_LEN / CS_CHUNKS)   // 32

// workspace layout (float offsets)
#define WS_PART   0                              // CS_CHUNKS*E_DIM (4 MB)
#define WS_COLSUM (WS_PART + CS_CHUNKS * E_DIM)  // 2048
#define WS_HH0    (WS_COLSUM + E_DIM)            // 4096 (w_hh_l0@h0 + biases)
#define WS_HH1    (WS_HH0 + G_DIM)               // 4096 (w_hh_l1@h1in + biases)
#define WS_G0     (WS_HH1 + G_DIM)               // 4096
#define WS_G1     (WS_G0 + G_DIM)                // 4096

typedef float fvec4 __attribute__((ext_vector_type(4)));

__device__ __forceinline__ float wave_sum(float v) {
#pragma unroll
  for (int off = 32; off > 0; off >>= 1) v += __shfl_down(v, off);
  return v;
}
__device__ __forceinline__ float dot4(fvec4 a, fvec4 b) {
  return a.x * b.x + a.y * b.y + a.z * b.z + a.w * b.w;
}
__device__ __forceinline__ fvec4 ntload(const fvec4* p) {
  return __builtin_nontemporal_load(p);
}
__device__ __forceinline__ float sigm(float x) { return 1.f / (1.f + expf(-x)); }

// ---------------------------------------------------------------------------
// K1: pure uniform enc stream (128 MB). 1024 blocks x 256 thr, 32 rows each.
__global__ __launch_bounds__(256) void colsum_partial_k(
    const fvec4* __restrict__ enc, fvec4* __restrict__ part) {
  int e4 = (blockIdx.x & 1) * 256 + threadIdx.x;  // 0..511
  int chunk = blockIdx.x >> 1;                    // 0..511
  fvec4 acc = {0.f, 0.f, 0.f, 0.f};
  size_t base = (size_t)chunk * CS_ROWS * 512 + e4;
#pragma unroll 16
  for (int r = 0; r < CS_ROWS; ++r) acc += ntload(&enc[base + (size_t)r * 512]);
  part[(size_t)chunk * 512 + e4] = acc;
}

// ---------------------------------------------------------------------------
// K2: blocks 0..31   -> colsum final (fixed-order, deterministic)
//     blocks 32..1055  -> hh0 rows (w_hh_l0 @ h0 + b_ih0 + b_hh0)
//     blocks 1056..2079-> hh1 rows (w_hh_l1 @ h1in + b_ih1 + b_hh1)
__global__ __launch_bounds__(256) void final_hh_k(
    const float* __restrict__ part, const fvec4* __restrict__ hidden,
    const fvec4* __restrict__ w_hh_l0,
    const float* __restrict__ b_ih_l0, const float* __restrict__ b_hh_l0,
    const fvec4* __restrict__ w_hh_l1,
    const float* __restrict__ b_ih_l1, const float* __restrict__ b_hh_l1,
    float* __restrict__ colsum, float* __restrict__ hh0,
    float* __restrict__ hh1) {
  int b = blockIdx.x;
  if (b < 32) {
    __shared__ float red[4][64];
    int lane = threadIdx.x & 63;
    int grp = threadIdx.x >> 6;         // 0..3
    int col = b * 64 + lane;            // 0..2047
    float acc = 0.f;
    int c0 = grp * (CS_CHUNKS / 4);
#pragma unroll 8
    for (int ch = c0; ch < c0 + CS_CHUNKS / 4; ++ch)
      acc += part[(size_t)ch * E_DIM + col];
    red[grp][lane] = acc;
    __syncthreads();
    if (threadIdx.x < 64) {
      float s = (red[0][lane] + red[1][lane]) + (red[2][lane] + red[3][lane]);
      colsum[col] = s;
    }
  } else {
    int which = (b >= 32 + 1024) ? 1 : 0;
    int wave = threadIdx.x >> 6;
    int lane = threadIdx.x & 63;
    int row = ((b - 32) & 1023) * 4 + wave;  // 0..4095
    const fvec4* w = (which ? w_hh_l1 : w_hh_l0) + (size_t)row * 256;
    const fvec4* h = hidden + (which ? 256 : 0);
    float a = 0.f;
#pragma unroll
    for (int k = lane; k < 256; k += 64) a += dot4(ntload(&w[k]), h[k]);
    a = wave_sum(a);
    if (lane == 0) {
      float bias = which ? (b_ih_l1[row] + b_hh_l1[row])
                         : (b_ih_l0[row] + b_hh_l0[row]);
      (which ? hh1 : hh0)[row] = a + bias;
    }
  }
}

// ---------------------------------------------------------------------------
// K3: g0[row] = w_ih_l0[row,:] @ colsum + hh0[row]
__global__ __launch_bounds__(256) void gates0_k(
    const fvec4* __restrict__ w_ih, const fvec4* __restrict__ x,
    const float* __restrict__ hh0, float* __restrict__ g0) {
  int wave = threadIdx.x >> 6;
  int lane = threadIdx.x & 63;
  int row = blockIdx.x * 4 + wave;  // < 4096
  const fvec4* wi = w_ih + (size_t)row * 512;
  float a = 0.f;
#pragma unroll
  for (int k = lane; k < 512; k += 64) a += dot4(ntload(&wi[k]), x[k]);
  a = wave_sum(a);
  if (lane == 0) g0[row] = a + hh0[row];
}

// ---------------------------------------------------------------------------
// K4: cell-0 prologue (h1 into LDS, redundant per block), then
//     g1[row] = w_ih_l1[row,:] @ h1 + hh1[row]
__global__ __launch_bounds__(256) void gates1_cell0_k(
    const float* __restrict__ g0, const float* __restrict__ c0,
    const fvec4* __restrict__ w_ih, const float* __restrict__ hh1,
    float* __restrict__ g1) {
  __shared__ __align__(16) float h1s[H_DIM];
#pragma unroll
  for (int k = 0; k < 4; ++k) {
    int j = threadIdx.x + 256 * k;
    float ig = g0[j], fg = g0[H_DIM + j], gg = g0[2 * H_DIM + j],
          og = g0[3 * H_DIM + j];
    float c2 = sigm(fg) * c0[j] + sigm(ig) * tanhf(gg);
    h1s[j] = sigm(og) * tanhf(c2);
  }
  __syncthreads();

  int wave = threadIdx.x >> 6;
  int lane = threadIdx.x & 63;
  int row = blockIdx.x * 4 + wave;  // < 4096
  const fvec4* h14 = (const fvec4*)h1s;
  const fvec4* wi = w_ih + (size_t)row * 256;
  float a = 0.f;
#pragma unroll
  for (int k = lane; k < 256; k += 64) a += dot4(ntload(&wi[k]), h14[k]);
  a = wave_sum(a);
  if (lane == 0) g1[row] = a + hh1[row];
}

// ---------------------------------------------------------------------------
// K5: 5 blocks, one output each. Each block: cell-1 (redundant) then dot.
__global__ __launch_bounds__(512) void fc_cell1_k(
    const float* __restrict__ g1, const float* __restrict__ c1,
    const float* __restrict__ fc_w, const float* __restrict__ fc_b,
    float* __restrict__ out) {
  __shared__ __align__(16) float h2s[H_DIM];
  __shared__ float red[8];
#pragma unroll
  for (int k = 0; k < 2; ++k) {
    int j = threadIdx.x + 512 * k;
    float ig = g1[j], fg = g1[H_DIM + j], gg = g1[2 * H_DIM + j],
          og = g1[3 * H_DIM + j];
    float c2 = sigm(fg) * c1[j] + sigm(ig) * tanhf(gg);
    h2s[j] = sigm(og) * tanhf(c2);
  }
  __syncthreads();

  int r = blockIdx.x;  // 0..4
  int wave = threadIdx.x >> 6;  // 0..7
  int lane = threadIdx.x & 63;
  const float* wr = fc_w + (size_t)r * H_DIM;
  // 512 threads x 2 elements, fixed order: thread t handles j=t and j=t+512
  float a = wr[threadIdx.x] * h2s[threadIdx.x] +
            wr[threadIdx.x + 512] * h2s[threadIdx.x + 512];
  a = wave_sum(a);
  if (lane == 0) red[wave] = a;
  __syncthreads();
  if (threadIdx.x == 0) {
    float s = ((red[0] + red[1]) + (red[2] + red[3])) +
              ((red[4] + red[5]) + (red[6] + red[7]));
    out[r] = s + fc_b[r];
  }
}

// ---------------------------------------------------------------------------
extern "C" void kernel_launch(void* const* d_in, const int* in_sizes, int n_in,
                              void* d_out, int out_size, void* d_ws, size_t ws_size,
                              hipStream_t stream) {
  const float* enc     = (const float*)d_in[0];   // (S,1,E)
  const float* hidden  = (const float*)d_in[1];   // (2,1,H)
  const float* c_in    = (const float*)d_in[2];   // (2,1,H)
  // d_in[3] attn_w, d_in[4] attn_b: dead (softmax over size-1 axis == 1)
  const float* w_ih_l0 = (const float*)d_in[5];   // (4H, E)
  const float* w_hh_l0 = (const float*)d_in[6];   // (4H, H)
  const float* b_ih_l0 = (const float*)d_in[7];
  const float* b_hh_l0 = (const float*)d_in[8];
  const float* w_ih_l1 = (const float*)d_in[9];   // (4H, H)
  const float* w_hh_l1 = (const float*)d_in[10];  // (4H, H)
  const float* b_ih_l1 = (const float*)d_in[11];
  const float* b_hh_l1 = (const float*)d_in[12];
  const float* fc_w    = (const float*)d_in[13];  // (C, H)
  const float* fc_b    = (const float*)d_in[14];

  float* ws = (float*)d_ws;
  float* part   = ws + WS_PART;
  float* colsum = ws + WS_COLSUM;
  float* hh0    = ws + WS_HH0;
  float* hh1    = ws + WS_HH1;
  float* g0     = ws + WS_G0;
  float* g1     = ws + WS_G1;
  float* out    = (float*)d_out;

  // K1: pure enc stream -> partials (128 MB)
  colsum_partial_k<<<2 * CS_CHUNKS, 256, 0, stream>>>(
      (const fvec4*)enc, (fvec4*)part);

  // K2: colsum final (32 blocks) + hh0/hh1 matvecs (2048 blocks, 32 MB)
  final_hh_k<<<32 + 2 * 1024, 256, 0, stream>>>(
      part, (const fvec4*)hidden,
      (const fvec4*)w_hh_l0, b_ih_l0, b_hh_l0,
      (const fvec4*)w_hh_l1, b_ih_l1, b_hh_l1,
      colsum, hh0, hh1);

  // K3: gates0 ih-part (32 MB)
  gates0_k<<<G_DIM / 4, 256, 0, stream>>>(
      (const fvec4*)w_ih_l0, (const fvec4*)colsum, hh0, g0);

  // K4: cell-0 (fused) + gates1 ih-part (16 MB)
  gates1_cell0_k<<<G_DIM / 4, 256, 0, stream>>>(
      g0, c_in, (const fvec4*)w_ih_l1, hh1, g1);

  // K5: cell-1 (fused) + FC, 5 parallel blocks
  fc_cell1_k<<<C_DIM, 512, 0, stream>>>(
      g1, c_in + H_DIM, fc_w, fc_b, out);
}